// Round 2
// baseline (987.874 us; speedup 1.0000x reference)
//
#include <hip/hip_runtime.h>
#include <math.h>

typedef float f32x4 __attribute__((ext_vector_type(4)));
typedef short s16x8 __attribute__((ext_vector_type(8)));

static constexpr int BL = 32768;   // B*L rows
static constexpr int E_DIM = 1280;
static constexpr int V_DIM = 32;
static constexpr int P_DIM = 496;
static constexpr int N2 = 640;     // padded V+P (528 -> 640)

#define DEV __device__ __forceinline__

DEV unsigned short f2bf(float f) {
  unsigned u = __float_as_uint(f);
  unsigned r = (u + 0x7fffu + ((u >> 16) & 1u)) >> 16;  // RNE
  return (unsigned short)r;
}
DEV float bf2f(unsigned short h) { return __uint_as_float(((unsigned)h) << 16); }

// ---------------------------------------------------------------------------
// Mask decode: the harness may deliver the bool mask as int32[32] or uint8[32].
// Sniff: read the first 8 words (32 bytes -- in-bounds under BOTH dtypes).
// If all 8 are 0/1 -> int32 layout; else (e.g. 0x01010101 from uint8 ones) ->
// uint8 layout. Decode to float[32] in ws.
// ---------------------------------------------------------------------------
__global__ void decode_mask_kernel(const void* __restrict__ mraw, float* __restrict__ out) {
  const int t = threadIdx.x;  // 64 threads, one wave
  const int* mi = (const int*)mraw;
  const unsigned char* mc = (const unsigned char*)mraw;
  bool ok = true;
  if (t < 8) {
    int v = mi[t];
    ok = (v == 0) || (v == 1);
  }
  unsigned long long bal = __ballot(ok);
  const bool useInt = ((bal & 0xFFull) == 0xFFull);
  if (t < 32) {
    float m;
    if (useInt) m = (mi[t] != 0) ? 1.0f : 0.0f;
    else        m = (mc[t] != 0) ? 1.0f : 0.0f;
    out[t] = m;
  }
}

// ---------------------------------------------------------------------------
// Weight prep: transpose to n-major [N][K] and split fp32 -> bf16 hi(/lo)
// ---------------------------------------------------------------------------
__global__ __launch_bounds__(256) void build_wt1_kernel(const float* __restrict__ w,
                                                        unsigned short* __restrict__ thi,
                                                        unsigned short* __restrict__ tlo) {
  __shared__ float tile[32][33];
  const int tx = threadIdx.x & 31, ty = threadIdx.x >> 5;  // 32 x 8
  const int k0 = blockIdx.x * 32, n0 = blockIdx.y * 32;
#pragma unroll
  for (int r = ty; r < 32; r += 8) tile[r][tx] = w[(size_t)(k0 + r) * E_DIM + (n0 + tx)];
  __syncthreads();
#pragma unroll
  for (int r = ty; r < 32; r += 8) {
    float v = tile[tx][r];  // = w[k0+tx][n0+r]
    unsigned short h = f2bf(v);
    size_t o = (size_t)(n0 + r) * E_DIM + (k0 + tx);
    thi[o] = h;
    if (tlo) tlo[o] = f2bf(v - bf2f(h));
  }
}

// W2 = [theta_w | Theta_w | zeros] -> n-major [640][1280], split hi(/lo)
__global__ __launch_bounds__(256) void build_wt2_kernel(const float* __restrict__ theta_w,
                                                        const float* __restrict__ Theta_w,
                                                        unsigned short* __restrict__ thi,
                                                        unsigned short* __restrict__ tlo) {
  __shared__ float tile[32][33];
  const int tx = threadIdx.x & 31, ty = threadIdx.x >> 5;
  const int k0 = blockIdx.x * 32, n0 = blockIdx.y * 32;
#pragma unroll
  for (int r = ty; r < 32; r += 8) {
    int n = n0 + tx, k = k0 + r;
    float v = 0.0f;
    if (n < V_DIM) v = theta_w[(size_t)k * V_DIM + n];
    else if (n < V_DIM + P_DIM) v = Theta_w[(size_t)k * P_DIM + (n - V_DIM)];
    tile[r][tx] = v;
  }
  __syncthreads();
#pragma unroll
  for (int r = ty; r < 32; r += 8) {
    float v = tile[tx][r];
    unsigned short h = f2bf(v);
    size_t o = (size_t)(n0 + r) * E_DIM + (k0 + tx);
    thi[o] = h;
    if (tlo) tlo[o] = f2bf(v - bf2f(h));
  }
}

__global__ void build_b2_kernel(const float* __restrict__ theta_b,
                                const float* __restrict__ Theta_b, float* __restrict__ b2) {
  int n = threadIdx.x;  // 640 threads
  float v = 0.0f;
  if (n < V_DIM) v = theta_b[n];
  else if (n < V_DIM + P_DIM) v = Theta_b[n - V_DIM];
  b2[n] = v;
}

// ---------------------------------------------------------------------------
// split GEMM: C[M x N] = A[M x 1280] * Wt[N x 1280]^T  (TN)
// EPI 0: A = fp32 hx (split on the fly); out = gelu(acc+bias) as bf16 hi(/lo)
// EPI 1: A = bf16 hi(/lo) (h);           out = acc+bias as fp32 (ld = 640)
// LO: use 3-term bf16 split (hi*hi + hi*lo + lo*hi); else plain bf16.
// ---------------------------------------------------------------------------
template <int EPI, bool LO>
__global__ __launch_bounds__(256) void gemm3_kernel(
    const float* __restrict__ Afp,
    const unsigned short* __restrict__ Ahi, const unsigned short* __restrict__ Alo,
    const unsigned short* __restrict__ Bhi, const unsigned short* __restrict__ Blo,
    const float* __restrict__ bias,
    unsigned short* __restrict__ OutHi, unsigned short* __restrict__ OutLo,
    float* __restrict__ OutF, int ldo) {
  constexpr int BM = 128, BN = 128, BK = 32, KD = 1280;
  __shared__ unsigned short Ah[BM * BK];
  __shared__ unsigned short Bh[BN * BK];
  __shared__ unsigned short Al[LO ? BM * BK : 64];
  __shared__ unsigned short Bl[LO ? BN * BK : 64];

  const int t = threadIdx.x;
  const int lane = t & 63;
  const int w = t >> 6;
  const int wm = (w >> 1) * 64;
  const int wn = (w & 1) * 64;

  // XCD-bijective swizzle: 256 m-tiles (fastest) -> per-XCD contiguous
  // m-slabs keep the Wt panel L2-resident.
  unsigned flat = blockIdx.y * 256u + blockIdx.x;
  unsigned total = gridDim.x * gridDim.y;          // multiple of 8
  unsigned logical = (flat & 7u) * (total >> 3) + (flat >> 3);
  const int m0 = (int)(logical & 255u) * BM;
  const int n0 = (int)(logical >> 8) * BN;

  f32x4 acc[4][4] = {};

  const int rl = lane & 15;
  const int kb = (lane >> 4) * 8;  // k element offset of this lane's fragment

  for (int kt = 0; kt < KD; kt += BK) {
    // ---- stage B (async global->LDS, 16B/lane, linear dest) ----
#pragma unroll
    for (int i = 0; i < 2; ++i) {
      int c = t + 256 * i;           // 0..511 chunks of 16B
      int row = c >> 2;              // 0..127 (n within tile)
      int kc = (c & 3) * 8;          // 0,8,16,24
      size_t go = (size_t)(n0 + row) * KD + kt + kc;
      __builtin_amdgcn_global_load_lds(
          (const __attribute__((address_space(1))) unsigned int*)(Bhi + go),
          (__attribute__((address_space(3))) unsigned int*)(Bh + c * 8), 16, 0, 0);
      if constexpr (LO)
        __builtin_amdgcn_global_load_lds(
            (const __attribute__((address_space(1))) unsigned int*)(Blo + go),
            (__attribute__((address_space(3))) unsigned int*)(Bl + c * 8), 16, 0, 0);
    }
    // ---- stage A ----
    if constexpr (EPI == 0) {
      // fp32 source, split to hi(/lo) in registers, ds_write
#pragma unroll
      for (int i = 0; i < 4; ++i) {
        int c = t + 256 * i;          // 0..1023 chunks of 4 floats
        int row = c >> 3;             // 0..127
        int c4 = (c & 7) * 4;         // 0..28
        const float4 v = *(const float4*)(Afp + (size_t)(m0 + row) * KD + kt + c4);
        ushort4 hh;
        hh.x = f2bf(v.x); hh.y = f2bf(v.y); hh.z = f2bf(v.z); hh.w = f2bf(v.w);
        *(ushort4*)(Ah + row * BK + c4) = hh;
        if constexpr (LO) {
          ushort4 ll;
          ll.x = f2bf(v.x - bf2f(hh.x));
          ll.y = f2bf(v.y - bf2f(hh.y));
          ll.z = f2bf(v.z - bf2f(hh.z));
          ll.w = f2bf(v.w - bf2f(hh.w));
          *(ushort4*)(Al + row * BK + c4) = ll;
        }
      }
    } else {
#pragma unroll
      for (int i = 0; i < 2; ++i) {
        int c = t + 256 * i;
        int row = c >> 2;
        int kc = (c & 3) * 8;
        size_t go = (size_t)(m0 + row) * KD + kt + kc;
        __builtin_amdgcn_global_load_lds(
            (const __attribute__((address_space(1))) unsigned int*)(Ahi + go),
            (__attribute__((address_space(3))) unsigned int*)(Ah + c * 8), 16, 0, 0);
        if constexpr (LO)
          __builtin_amdgcn_global_load_lds(
              (const __attribute__((address_space(1))) unsigned int*)(Alo + go),
              (__attribute__((address_space(3))) unsigned int*)(Al + c * 8), 16, 0, 0);
      }
    }
    __syncthreads();

    // ---- fragments: contiguous-K ds_read_b128 ----
    s16x8 afh[4], afl[4], bfh[4], bfl[4];
#pragma unroll
    for (int mi = 0; mi < 4; ++mi) {
      int r = wm + mi * 16 + rl;
      afh[mi] = *(const s16x8*)(Ah + r * BK + kb);
      if constexpr (LO) afl[mi] = *(const s16x8*)(Al + r * BK + kb);
    }
#pragma unroll
    for (int ni = 0; ni < 4; ++ni) {
      int r = wn + ni * 16 + rl;
      bfh[ni] = *(const s16x8*)(Bh + r * BK + kb);
      if constexpr (LO) bfl[ni] = *(const s16x8*)(Bl + r * BK + kb);
    }
    // ---- split product ----
#pragma unroll
    for (int mi = 0; mi < 4; ++mi)
#pragma unroll
      for (int ni = 0; ni < 4; ++ni) {
        acc[mi][ni] = __builtin_amdgcn_mfma_f32_16x16x32_bf16(afh[mi], bfh[ni], acc[mi][ni], 0, 0, 0);
        if constexpr (LO) {
          acc[mi][ni] = __builtin_amdgcn_mfma_f32_16x16x32_bf16(afh[mi], bfl[ni], acc[mi][ni], 0, 0, 0);
          acc[mi][ni] = __builtin_amdgcn_mfma_f32_16x16x32_bf16(afl[mi], bfh[ni], acc[mi][ni], 0, 0, 0);
        }
      }
    __syncthreads();
  }

  // ---- epilogue: C/D layout col = lane&15 (from B), row = (lane>>4)*4 + r (from A)
  const int rb = (lane >> 4) * 4;
  const int cl = lane & 15;
#pragma unroll
  for (int mi = 0; mi < 4; ++mi) {
#pragma unroll
    for (int ni = 0; ni < 4; ++ni) {
      const int gc = n0 + wn + ni * 16 + cl;
      const float bsv = bias[gc];
#pragma unroll
      for (int r = 0; r < 4; ++r) {
        const int gr = m0 + wm + mi * 16 + rb + r;
        float x = acc[mi][ni][r] + bsv;
        if constexpr (EPI == 0) {
          float g = 0.5f * x * (1.0f + erff(x * 0.7071067811865476f));  // exact gelu
          unsigned short hh = f2bf(g);
          OutHi[(size_t)gr * ldo + gc] = hh;
          if constexpr (LO) OutLo[(size_t)gr * ldo + gc] = f2bf(g - bf2f(hh));
        } else {
          OutF[(size_t)gr * ldo + gc] = x;
        }
      }
    }
  }
}

// ---------------------------------------------------------------------------
// LayerNorm over E=1280, in place on the bf16 hi(/lo) pair. One block per row,
// 320 threads x ushort4.
// ---------------------------------------------------------------------------
__global__ __launch_bounds__(320) void ln_kernel(unsigned short* __restrict__ hhi,
                                                 unsigned short* __restrict__ hlo,
                                                 const float* __restrict__ gw,
                                                 const float* __restrict__ bw) {
  const size_t base = (size_t)blockIdx.x * E_DIM;
  const int t = threadIdx.x;  // 0..319
  const int lane = t & 63, w = t >> 6;
  const size_t off = base + (size_t)t * 4;
  const ushort4 hv = *(const ushort4*)(hhi + off);
  float v0 = bf2f(hv.x), v1 = bf2f(hv.y), v2 = bf2f(hv.z), v3 = bf2f(hv.w);
  if (hlo) {
    const ushort4 lv = *(const ushort4*)(hlo + off);
    v0 += bf2f(lv.x); v1 += bf2f(lv.y); v2 += bf2f(lv.z); v3 += bf2f(lv.w);
  }
  float s = v0 + v1 + v2 + v3;
  float sq = v0 * v0 + v1 * v1 + v2 * v2 + v3 * v3;
#pragma unroll
  for (int o = 32; o >= 1; o >>= 1) { s += __shfl_xor(s, o); sq += __shfl_xor(sq, o); }
  __shared__ float ls[5], lq[5];
  if (lane == 0) { ls[w] = s; lq[w] = sq; }
  __syncthreads();
  s = ls[0] + ls[1] + ls[2] + ls[3] + ls[4];
  sq = lq[0] + lq[1] + lq[2] + lq[3] + lq[4];
  const float mu = s * (1.0f / E_DIM);
  const float var = sq * (1.0f / E_DIM) - mu * mu;
  const float rstd = rsqrtf(var + 1e-12f);
  const float4 g4 = *(const float4*)(gw + (size_t)t * 4);
  const float4 b4 = *(const float4*)(bw + (size_t)t * 4);
  const float y0 = (v0 - mu) * rstd * g4.x + b4.x;
  const float y1 = (v1 - mu) * rstd * g4.y + b4.y;
  const float y2 = (v2 - mu) * rstd * g4.z + b4.z;
  const float y3 = (v3 - mu) * rstd * g4.w + b4.w;
  ushort4 oh;
  oh.x = f2bf(y0); oh.y = f2bf(y1); oh.z = f2bf(y2); oh.w = f2bf(y3);
  *(ushort4*)(hhi + off) = oh;
  if (hlo) {
    ushort4 ol;
    ol.x = f2bf(y0 - bf2f(oh.x));
    ol.y = f2bf(y1 - bf2f(oh.y));
    ol.z = f2bf(y2 - bf2f(oh.z));
    ol.w = f2bf(y3 - bf2f(oh.w));
    *(ushort4*)(hlo + off) = ol;
  }
}

// ---------------------------------------------------------------------------
// Q build: per wave = one (b,l) position. Masked log-softmax over V=32,
// softplus(Theta), Pande transform, row sums, diag correction.
// ---------------------------------------------------------------------------
__global__ __launch_bounds__(256) void qbuild_kernel(const float* __restrict__ g2,
                                                     const float* __restrict__ maskf,
                                                     float* __restrict__ Qout,
                                                     float* __restrict__ piOut) {
  __shared__ float sS[4][P_DIM];
  __shared__ float sR[4][V_DIM];
  __shared__ float sC[4][V_DIM];
  const int t = threadIdx.x;
  const int w = t >> 6, lane = t & 63;
  const int p = blockIdx.x * 4 + w;
  const float* row = g2 + (size_t)p * N2;

  // masked log-softmax on logits (both half-waves compute identically)
  const int c = lane & 31;
  const bool mv = maskf[c] != 0.0f;
  const float xm = mv ? row[c] : -INFINITY;
  float mx = xm;
#pragma unroll
  for (int o = 16; o >= 1; o >>= 1) mx = fmaxf(mx, __shfl_xor(mx, o, 32));
  const float e = mv ? expf(xm - mx) : 0.0f;
  float se = e;
#pragma unroll
  for (int o = 16; o >= 1; o >>= 1) se += __shfl_xor(se, o, 32);
  const float lp = xm - mx - logf(se);
  const float lps = mv ? lp : 0.0f;
  if (lane < 32) {
    piOut[(size_t)p * V_DIM + lane] = mv ? expf(lp) : 0.0f;
    sR[w][lane] = mv ? expf(-0.5f * lps) : 0.0f;  // mask folded: rows/cols of S zeroed
    sC[w][lane] = mv ? expf(0.5f * lps) : 0.0f;
  }
  // softplus(Theta) into LDS
  for (int idx = lane; idx < P_DIM; idx += 64) {
    float tv = row[V_DIM + idx];
    sS[w][idx] = tv > 20.0f ? tv : log1pf(expf(tv));
  }
  __syncthreads();

  // Q entries: 16 sweeps x 64 lanes; each 32-lane group = one row of Q
#pragma unroll
  for (int t16 = 0; t16 < 16; ++t16) {
    const int eidx = t16 * 64 + lane;
    const int i = eidx >> 5, j = eidx & 31;
    float v = 0.0f;
    if (i != j) {
      const int a = i < j ? i : j;
      const int b = i < j ? j : i;
      const int pq = a * 31 - (a * (a - 1)) / 2 + (b - a - 1);
      v = sS[w][pq] * sR[w][i] * sC[w][j];
    }
    float r = v;
#pragma unroll
    for (int o = 16; o >= 1; o >>= 1) r += __shfl_xor(r, o, 32);
    Qout[(size_t)p * (V_DIM * V_DIM) + eidx] = (i == j) ? -r : v;
  }
}

// ---------------------------------------------------------------------------
extern "C" void kernel_launch(void* const* d_in, const int* in_sizes, int n_in,
                              void* d_out, int out_size, void* d_ws, size_t ws_size,
                              hipStream_t stream) {
  const float* hx = (const float*)d_in[0];
  const void* mask_raw = (const void*)d_in[1];
  const float* dense_w = (const float*)d_in[2];
  const float* dense_b = (const float*)d_in[3];
  const float* ln_g = (const float*)d_in[4];
  const float* ln_b = (const float*)d_in[5];
  const float* theta_w = (const float*)d_in[6];
  const float* theta_b = (const float*)d_in[7];
  const float* Theta_w = (const float*)d_in[8];
  const float* Theta_b = (const float*)d_in[9];

  char* ws = (char*)d_ws;
  // base buffers (always present)
  float* g2out = (float*)(ws + 0);                                //  83,886,080
  unsigned short* h_hi = (unsigned short*)(ws + 83886080ULL);     //  83,886,080
  unsigned short* wt1_hi = (unsigned short*)(ws + 167772160ULL);  //   3,276,800
  unsigned short* wt2_hi = (unsigned short*)(ws + 171048960ULL);  //   1,638,400
  float* b2 = (float*)(ws + 172687360ULL);                        //       2,560
  float* maskf = (float*)(ws + 172689920ULL);                     //         256
  // lo buffers (only if ws is big enough)
  const size_t FULL_NEED = 261491456ULL;
  const bool full = ws_size >= FULL_NEED;
  unsigned short* h_lo = full ? (unsigned short*)(ws + 172690176ULL) : nullptr;
  unsigned short* wt1_lo = full ? (unsigned short*)(ws + 256576256ULL) : nullptr;
  unsigned short* wt2_lo = full ? (unsigned short*)(ws + 259853056ULL) : nullptr;

  float* Qout = (float*)d_out;
  float* piOut = Qout + (size_t)BL * V_DIM * V_DIM;

  decode_mask_kernel<<<1, 64, 0, stream>>>(mask_raw, maskf);
  build_wt1_kernel<<<dim3(40, 40), 256, 0, stream>>>(dense_w, wt1_hi, wt1_lo);
  build_wt2_kernel<<<dim3(40, 20), 256, 0, stream>>>(theta_w, Theta_w, wt2_hi, wt2_lo);
  build_b2_kernel<<<1, 640, 0, stream>>>(theta_b, Theta_b, b2);

  if (full) {
    gemm3_kernel<0, true><<<dim3(256, 10), 256, 0, stream>>>(
        hx, nullptr, nullptr, wt1_hi, wt1_lo, dense_b, h_hi, h_lo, nullptr, E_DIM);
    ln_kernel<<<BL, 320, 0, stream>>>(h_hi, h_lo, ln_g, ln_b);
    gemm3_kernel<1, true><<<dim3(256, 5), 256, 0, stream>>>(
        nullptr, h_hi, h_lo, wt2_hi, wt2_lo, b2, nullptr, nullptr, g2out, N2);
  } else {
    gemm3_kernel<0, false><<<dim3(256, 10), 256, 0, stream>>>(
        hx, nullptr, nullptr, wt1_hi, nullptr, dense_b, h_hi, nullptr, nullptr, E_DIM);
    ln_kernel<<<BL, 320, 0, stream>>>(h_hi, nullptr, ln_g, ln_b);
    gemm3_kernel<1, false><<<dim3(256, 5), 256, 0, stream>>>(
        nullptr, h_hi, nullptr, wt2_hi, nullptr, b2, nullptr, nullptr, g2out, N2);
  }
  qbuild_kernel<<<8192, 256, 0, stream>>>(g2out, maskf, Qout, piOut);
}

// Round 3
// 908.229 us; speedup vs baseline: 1.0877x; 1.0877x over previous
//
#include <hip/hip_runtime.h>
#include <math.h>

typedef float f32x4 __attribute__((ext_vector_type(4)));
typedef short s16x8 __attribute__((ext_vector_type(8)));

static constexpr int BL = 32768;   // B*L rows
static constexpr int E_DIM = 1280;
static constexpr int V_DIM = 32;
static constexpr int P_DIM = 496;
static constexpr int N2 = 640;     // padded V+P (528 -> 640)

#define DEV __device__ __forceinline__

DEV unsigned short f2bf(float f) {
  unsigned u = __float_as_uint(f);
  unsigned r = (u + 0x7fffu + ((u >> 16) & 1u)) >> 16;  // RNE
  return (unsigned short)r;
}
DEV float bf2f(unsigned short h) { return __uint_as_float(((unsigned)h) << 16); }

// ---------------------------------------------------------------------------
// Mask decode (dtype sniff: int32[32] vs uint8[32] -> float[32])
// ---------------------------------------------------------------------------
__global__ void decode_mask_kernel(const void* __restrict__ mraw, float* __restrict__ out) {
  const int t = threadIdx.x;  // 64 threads
  const int* mi = (const int*)mraw;
  const unsigned char* mc = (const unsigned char*)mraw;
  bool ok = true;
  if (t < 8) {
    int v = mi[t];
    ok = (v == 0) || (v == 1);
  }
  unsigned long long bal = __ballot(ok);
  const bool useInt = ((bal & 0xFFull) == 0xFFull);
  if (t < 32) {
    float m;
    if (useInt) m = (mi[t] != 0) ? 1.0f : 0.0f;
    else        m = (mc[t] != 0) ? 1.0f : 0.0f;
    out[t] = m;
  }
}

// ---------------------------------------------------------------------------
// hx fp32 -> bf16 (RNE), one elementwise pass
// ---------------------------------------------------------------------------
__global__ __launch_bounds__(256) void f32_to_bf16_kernel(const float* __restrict__ in,
                                                          unsigned short* __restrict__ out,
                                                          int n4) {
  int idx = blockIdx.x * 256 + threadIdx.x;
  const int stride = gridDim.x * 256;
  for (; idx < n4; idx += stride) {
    const float4 v = *(const float4*)(in + (size_t)idx * 4);
    ushort4 o;
    o.x = f2bf(v.x); o.y = f2bf(v.y); o.z = f2bf(v.z); o.w = f2bf(v.w);
    *(ushort4*)(out + (size_t)idx * 4) = o;
  }
}

// ---------------------------------------------------------------------------
// Weight prep: transpose to n-major [N][K], fp32 -> bf16
// ---------------------------------------------------------------------------
__global__ __launch_bounds__(256) void build_wt1_kernel(const float* __restrict__ w,
                                                        unsigned short* __restrict__ thi) {
  __shared__ float tile[32][33];
  const int tx = threadIdx.x & 31, ty = threadIdx.x >> 5;  // 32 x 8
  const int k0 = blockIdx.x * 32, n0 = blockIdx.y * 32;
#pragma unroll
  for (int r = ty; r < 32; r += 8) tile[r][tx] = w[(size_t)(k0 + r) * E_DIM + (n0 + tx)];
  __syncthreads();
#pragma unroll
  for (int r = ty; r < 32; r += 8)
    thi[(size_t)(n0 + r) * E_DIM + (k0 + tx)] = f2bf(tile[tx][r]);
}

__global__ __launch_bounds__(256) void build_wt2_kernel(const float* __restrict__ theta_w,
                                                        const float* __restrict__ Theta_w,
                                                        unsigned short* __restrict__ thi) {
  __shared__ float tile[32][33];
  const int tx = threadIdx.x & 31, ty = threadIdx.x >> 5;
  const int k0 = blockIdx.x * 32, n0 = blockIdx.y * 32;
#pragma unroll
  for (int r = ty; r < 32; r += 8) {
    int n = n0 + tx, k = k0 + r;
    float v = 0.0f;
    if (n < V_DIM) v = theta_w[(size_t)k * V_DIM + n];
    else if (n < V_DIM + P_DIM) v = Theta_w[(size_t)k * P_DIM + (n - V_DIM)];
    tile[r][tx] = v;
  }
  __syncthreads();
#pragma unroll
  for (int r = ty; r < 32; r += 8)
    thi[(size_t)(n0 + r) * E_DIM + (k0 + tx)] = f2bf(tile[tx][r]);
}

__global__ void build_b2_kernel(const float* __restrict__ theta_b,
                                const float* __restrict__ Theta_b, float* __restrict__ b2) {
  int n = threadIdx.x;  // 640 threads
  float v = 0.0f;
  if (n < V_DIM) v = theta_b[n];
  else if (n < V_DIM + P_DIM) v = Theta_b[n - V_DIM];
  b2[n] = v;
}

// ---------------------------------------------------------------------------
// bf16 GEMM: C[M x N] = A[M x 1280] * B[N x 1280]^T  (TN, both bf16 n/m-major)
// Double-buffered LDS, K-major conflict-free layout, global_load_lds width 16.
// EPI 0: out = gelu(acc + bias) -> bf16 (ldo = 1280)
// EPI 1: out = acc + bias       -> fp32 (ldo = 640)
// ---------------------------------------------------------------------------
template <int EPI>
__global__ __launch_bounds__(256, 4) void gemm_bf16_kernel(
    const unsigned short* __restrict__ A, const unsigned short* __restrict__ B,
    const float* __restrict__ bias, unsigned short* __restrict__ OutBf,
    float* __restrict__ OutF, int ldo) {
  constexpr int BK = 32, KD = 1280, NKT = KD / BK;  // 40 K-steps
  // K-major LDS: chunk c in [0,512): q = c>>7 (k-slot), row = c&127.
  // elem offset = c*8. Frag read (q,row) -> byte q*2048 + row*16: 16 lanes of a
  // quarter-group span banks 4r%32 -> exactly 2 lanes/bank (free, m136).
  __shared__ __align__(16) unsigned short As[2][128 * BK];
  __shared__ __align__(16) unsigned short Bs[2][128 * BK];

  const int t = threadIdx.x;
  const int lane = t & 63;
  const int w = t >> 6;
  const int wm = (w >> 1) * 64, wn = (w & 1) * 64;

  // XCD-bijective swizzle: m fastest (gridDim.x == 256 m-tiles); per-XCD
  // contiguous logical range keeps the whole Wt matrix L2-resident.
  unsigned flat = blockIdx.y * 256u + blockIdx.x;
  unsigned total = gridDim.x * gridDim.y;          // multiple of 8
  unsigned logical = (flat & 7u) * (total >> 3) + (flat >> 3);
  const int m0 = (int)(logical & 255u) * 128;
  const int n0 = (int)(logical >> 8) * 128;

  // staging: thread t owns chunks t and t+256 of each tile
  const int q0 = t >> 7, r0 = t & 127;
  const int c1 = t + 256;
  const int q1 = c1 >> 7, r1 = c1 & 127;
  const unsigned short* a0 = A + (size_t)(m0 + r0) * KD + q0 * 8;
  const unsigned short* a1 = A + (size_t)(m0 + r1) * KD + q1 * 8;
  const unsigned short* b0 = B + (size_t)(n0 + r0) * KD + q0 * 8;
  const unsigned short* b1 = B + (size_t)(n0 + r1) * KD + q1 * 8;

#define STAGE(buf, kt)                                                                  \
  do {                                                                                  \
    __builtin_amdgcn_global_load_lds(                                                   \
        (const __attribute__((address_space(1))) unsigned int*)(a0 + (kt)),             \
        (__attribute__((address_space(3))) unsigned int*)(&As[(buf)][t * 8]), 16, 0, 0);\
    __builtin_amdgcn_global_load_lds(                                                   \
        (const __attribute__((address_space(1))) unsigned int*)(a1 + (kt)),             \
        (__attribute__((address_space(3))) unsigned int*)(&As[(buf)][c1 * 8]), 16, 0, 0);\
    __builtin_amdgcn_global_load_lds(                                                   \
        (const __attribute__((address_space(1))) unsigned int*)(b0 + (kt)),             \
        (__attribute__((address_space(3))) unsigned int*)(&Bs[(buf)][t * 8]), 16, 0, 0);\
    __builtin_amdgcn_global_load_lds(                                                   \
        (const __attribute__((address_space(1))) unsigned int*)(b1 + (kt)),             \
        (__attribute__((address_space(3))) unsigned int*)(&Bs[(buf)][c1 * 8]), 16, 0, 0);\
  } while (0)

  f32x4 acc[4][4] = {};
  const int q = lane >> 4, r = lane & 15;
  const int abase = q * 1024 + (wm + r) * 8;  // + mi*128
  const int bbase = q * 1024 + (wn + r) * 8;  // + ni*128

  STAGE(0, 0);
  __syncthreads();  // drains vmcnt(0): buf0 staged

  int cur = 0;
  for (int ki = 0; ki < NKT - 1; ++ki) {
    STAGE(cur ^ 1, (ki + 1) * BK);  // issue next tile BEFORE compute (overlap)
    s16x8 af[4], bf[4];
#pragma unroll
    for (int mi = 0; mi < 4; ++mi) af[mi] = *(const s16x8*)(&As[cur][abase + mi * 128]);
#pragma unroll
    for (int ni = 0; ni < 4; ++ni) bf[ni] = *(const s16x8*)(&Bs[cur][bbase + ni * 128]);
#pragma unroll
    for (int mi = 0; mi < 4; ++mi)
#pragma unroll
      for (int ni = 0; ni < 4; ++ni)
        acc[mi][ni] = __builtin_amdgcn_mfma_f32_16x16x32_bf16(af[mi], bf[ni], acc[mi][ni], 0, 0, 0);
    __syncthreads();  // full waitcnt drain: next buf staged, this buf's reads done
    cur ^= 1;
  }
  {  // last tile: no prefetch
    s16x8 af[4], bf[4];
#pragma unroll
    for (int mi = 0; mi < 4; ++mi) af[mi] = *(const s16x8*)(&As[cur][abase + mi * 128]);
#pragma unroll
    for (int ni = 0; ni < 4; ++ni) bf[ni] = *(const s16x8*)(&Bs[cur][bbase + ni * 128]);
#pragma unroll
    for (int mi = 0; mi < 4; ++mi)
#pragma unroll
      for (int ni = 0; ni < 4; ++ni)
        acc[mi][ni] = __builtin_amdgcn_mfma_f32_16x16x32_bf16(af[mi], bf[ni], acc[mi][ni], 0, 0, 0);
  }
#undef STAGE

  // epilogue: C/D layout col = lane&15 (B-side), row = (lane>>4)*4 + reg (A-side)
  const int rb = (lane >> 4) * 4;
  const int cl = lane & 15;
#pragma unroll
  for (int mi = 0; mi < 4; ++mi) {
#pragma unroll
    for (int ni = 0; ni < 4; ++ni) {
      const int gc = n0 + wn + ni * 16 + cl;
      const float bsv = bias[gc];
#pragma unroll
      for (int rr = 0; rr < 4; ++rr) {
        const int gr = m0 + wm + mi * 16 + rb + rr;
        float x = acc[mi][ni][rr] + bsv;
        if constexpr (EPI == 0) {
          float g = 0.5f * x * (1.0f + erff(x * 0.7071067811865476f));  // exact gelu
          OutBf[(size_t)gr * ldo + gc] = f2bf(g);
        } else {
          OutF[(size_t)gr * ldo + gc] = x;
        }
      }
    }
  }
}

// ---------------------------------------------------------------------------
// LayerNorm over E=1280, in place on bf16. One block per row, 320 thr x ushort4.
// ---------------------------------------------------------------------------
__global__ __launch_bounds__(320) void ln_kernel(unsigned short* __restrict__ h,
                                                 const float* __restrict__ gw,
                                                 const float* __restrict__ bw) {
  const size_t base = (size_t)blockIdx.x * E_DIM;
  const int t = threadIdx.x;  // 0..319
  const int lane = t & 63, w = t >> 6;
  const size_t off = base + (size_t)t * 4;
  const ushort4 hv = *(const ushort4*)(h + off);
  const float v0 = bf2f(hv.x), v1 = bf2f(hv.y), v2 = bf2f(hv.z), v3 = bf2f(hv.w);
  float s = v0 + v1 + v2 + v3;
  float sq = v0 * v0 + v1 * v1 + v2 * v2 + v3 * v3;
#pragma unroll
  for (int o = 32; o >= 1; o >>= 1) { s += __shfl_xor(s, o); sq += __shfl_xor(sq, o); }
  __shared__ float ls[5], lq[5];
  if (lane == 0) { ls[w] = s; lq[w] = sq; }
  __syncthreads();
  s = ls[0] + ls[1] + ls[2] + ls[3] + ls[4];
  sq = lq[0] + lq[1] + lq[2] + lq[3] + lq[4];
  const float mu = s * (1.0f / E_DIM);
  const float var = sq * (1.0f / E_DIM) - mu * mu;
  const float rstd = rsqrtf(var + 1e-12f);
  const float4 g4 = *(const float4*)(gw + (size_t)t * 4);
  const float4 b4 = *(const float4*)(bw + (size_t)t * 4);
  ushort4 oh;
  oh.x = f2bf((v0 - mu) * rstd * g4.x + b4.x);
  oh.y = f2bf((v1 - mu) * rstd * g4.y + b4.y);
  oh.z = f2bf((v2 - mu) * rstd * g4.z + b4.z);
  oh.w = f2bf((v3 - mu) * rstd * g4.w + b4.w);
  *(ushort4*)(h + off) = oh;
}

// ---------------------------------------------------------------------------
// Q build: per wave = one (b,l). Masked log-softmax over V=32, softplus,
// Pande transform, row sums, diag correction.
// ---------------------------------------------------------------------------
__global__ __launch_bounds__(256) void qbuild_kernel(const float* __restrict__ g2,
                                                     const float* __restrict__ maskf,
                                                     float* __restrict__ Qout,
                                                     float* __restrict__ piOut) {
  __shared__ float sS[4][P_DIM];
  __shared__ float sR[4][V_DIM];
  __shared__ float sC[4][V_DIM];
  const int t = threadIdx.x;
  const int w = t >> 6, lane = t & 63;
  const int p = blockIdx.x * 4 + w;
  const float* row = g2 + (size_t)p * N2;

  const int c = lane & 31;
  const bool mv = maskf[c] != 0.0f;
  const float xm = mv ? row[c] : -INFINITY;
  float mx = xm;
#pragma unroll
  for (int o = 16; o >= 1; o >>= 1) mx = fmaxf(mx, __shfl_xor(mx, o, 32));
  const float e = mv ? expf(xm - mx) : 0.0f;
  float se = e;
#pragma unroll
  for (int o = 16; o >= 1; o >>= 1) se += __shfl_xor(se, o, 32);
  const float lp = xm - mx - logf(se);
  const float lps = mv ? lp : 0.0f;
  if (lane < 32) {
    piOut[(size_t)p * V_DIM + lane] = mv ? expf(lp) : 0.0f;
    sR[w][lane] = mv ? expf(-0.5f * lps) : 0.0f;  // mask folded into R/C
    sC[w][lane] = mv ? expf(0.5f * lps) : 0.0f;
  }
  for (int idx = lane; idx < P_DIM; idx += 64) {
    float tv = row[V_DIM + idx];
    sS[w][idx] = tv > 20.0f ? tv : log1pf(expf(tv));
  }
  __syncthreads();

#pragma unroll
  for (int t16 = 0; t16 < 16; ++t16) {
    const int eidx = t16 * 64 + lane;
    const int i = eidx >> 5, j = eidx & 31;
    float v = 0.0f;
    if (i != j) {
      const int a = i < j ? i : j;
      const int b = i < j ? j : i;
      const int pq = a * 31 - (a * (a - 1)) / 2 + (b - a - 1);
      v = sS[w][pq] * sR[w][i] * sC[w][j];
    }
    float rsum = v;
#pragma unroll
    for (int o = 16; o >= 1; o >>= 1) rsum += __shfl_xor(rsum, o, 32);
    Qout[(size_t)p * (V_DIM * V_DIM) + eidx] = (i == j) ? -rsum : v;
  }
}

// ---------------------------------------------------------------------------
extern "C" void kernel_launch(void* const* d_in, const int* in_sizes, int n_in,
                              void* d_out, int out_size, void* d_ws, size_t ws_size,
                              hipStream_t stream) {
  const float* hx = (const float*)d_in[0];
  const void* mask_raw = (const void*)d_in[1];
  const float* dense_w = (const float*)d_in[2];
  const float* dense_b = (const float*)d_in[3];
  const float* ln_g = (const float*)d_in[4];
  const float* ln_b = (const float*)d_in[5];
  const float* theta_w = (const float*)d_in[6];
  const float* theta_b = (const float*)d_in[7];
  const float* Theta_w = (const float*)d_in[8];
  const float* Theta_b = (const float*)d_in[9];

  char* ws = (char*)d_ws;
  // buf0: hx_bf during gemm1, then g2out (disjoint lifetimes) -- 83,886,080 B
  unsigned short* hx_bf = (unsigned short*)(ws + 0);
  float* g2out = (float*)(ws + 0);
  unsigned short* h_bf = (unsigned short*)(ws + 83886080ULL);     //  83,886,080
  unsigned short* wt1 = (unsigned short*)(ws + 167772160ULL);     //   3,276,800
  unsigned short* wt2 = (unsigned short*)(ws + 171048960ULL);     //   1,638,400
  float* b2 = (float*)(ws + 172687360ULL);                        //       2,560
  float* maskf = (float*)(ws + 172689920ULL);                     //         256
  // total: 172,690,176 B (same footprint as the passing round-2 config)

  float* Qout = (float*)d_out;
  float* piOut = Qout + (size_t)BL * V_DIM * V_DIM;

  decode_mask_kernel<<<1, 64, 0, stream>>>(mask_raw, maskf);
  build_wt1_kernel<<<dim3(40, 40), 256, 0, stream>>>(dense_w, wt1);
  build_wt2_kernel<<<dim3(40, 20), 256, 0, stream>>>(theta_w, Theta_w, wt2);
  build_b2_kernel<<<1, 640, 0, stream>>>(theta_b, Theta_b, b2);
  f32_to_bf16_kernel<<<2048, 256, 0, stream>>>(hx, hx_bf, BL * E_DIM / 4);

  // dense + gelu -> h (bf16)
  gemm_bf16_kernel<0><<<dim3(256, 10), 256, 0, stream>>>(hx_bf, wt1, dense_b, h_bf, nullptr, E_DIM);
  // layernorm in place
  ln_kernel<<<BL, 320, 0, stream>>>(h_bf, ln_g, ln_b);
  // h @ [theta|Theta] + bias -> fp32 (ld 640); overwrites hx_bf (dead)
  gemm_bf16_kernel<1><<<dim3(256, 5), 256, 0, stream>>>(h_bf, wt2, b2, nullptr, g2out, N2);
  // masked softmax + softplus + Pande transform + row-sum correction
  qbuild_kernel<<<8192, 256, 0, stream>>>(g2out, maskf, Qout, piOut);
}